// Round 2
// baseline (241.003 us; speedup 1.0000x reference)
//
#include <hip/hip_runtime.h>
#include <hip/hip_bf16.h>

// EgoAttentionNetwork: B=8192, E=64, F_IN=7, D=64, H=4, HD=16.  All fp32.
// K/V-elimination algebra:
//   scores[h,e] = Y[e,:] . (Wk[:,hcols] q[hcols])   (never build K)
//   out[h,:]    = (p_h . Y) . Wv[:,hcols]           (never build V)
// Block = 256 threads (4 waves) cooperating on one batch at a time; 16 batches/block.
// Grid 512 -> 2 blocks/CU (LDS ~44KB/block). lane = feature column.

#define E_  64
#define STR 68   // fp32 LDS row stride (breaks 64-stride bank conflicts)

__global__ __launch_bounds__(256, 2)
void ego_attn_kernel(const float* __restrict__ x,
                     const float* __restrict__ ego_w0, const float* __restrict__ ego_b0,
                     const float* __restrict__ ego_w1, const float* __restrict__ ego_b1,
                     const float* __restrict__ oth_w0, const float* __restrict__ oth_b0,
                     const float* __restrict__ oth_w1, const float* __restrict__ oth_b1,
                     const float* __restrict__ Wk, const float* __restrict__ Wv,
                     const float* __restrict__ Wq, const float* __restrict__ Wc,
                     float* __restrict__ out, int batches_per_block)
{
    __shared__ __align__(16) float xbuf[E_ * 8];     // x[e][i], i<7 (fp32)
    __shared__ __align__(16) float Hb[E_ * STR];     // layer-1 output (row0 = ego h0)
    __shared__ __align__(16) float Yb[E_ * STR];     // input_all (row0 = ego)
    __shared__ __align__(16) float egopart[4 * STR];
    __shared__ __align__(16) float qpart[4 * STR];
    __shared__ __align__(16) float qbuf[STR];
    __shared__ __align__(16) float kqb[4 * STR];     // kq per head
    __shared__ __align__(16) float pbuf[4 * STR];    // softmax probs per head
    __shared__ __align__(16) float pYb[4 * STR];     // p . Y per head
    __shared__ __align__(16) float opart[4 * STR];
    __shared__ __align__(16) float obuf[STR];        // attention output (64)
    __shared__ __align__(16) float rpart[4 * STR];

    const int tid = threadIdx.x;
    const int wv  = tid >> 6;    // wave 0..3 (also head id / row-range id)
    const int f   = tid & 63;    // feature column owned by this lane
    const int hf  = f >> 4;      // head that feature f belongs to

    // ---- register-cached weight columns (column f) ----
    float w0o[7], w0e[7];
#pragma unroll
    for (int i = 0; i < 7; ++i) {
        w0o[i] = oth_w0[i * 64 + f];
        w0e[i] = ego_w0[i * 64 + f];
    }
    const float b0o = oth_b0[f], b0e = ego_b0[f];
    const float b1o = oth_b1[f], b1e = ego_b1[f];
    float w1c[64];                       // oth_w1 column f (the big matmul)
#pragma unroll
    for (int j = 0; j < 64; ++j) w1c[j] = oth_w1[j * 64 + f];

    for (int bi = 0; bi < batches_per_block; ++bi) {
        const int b = blockIdx.x * batches_per_block + bi;
        const float* xb = x + (size_t)b * (E_ * 7);

        // P0: stage x into LDS (row stride 8)
        for (int idx = tid; idx < E_ * 7; idx += 256) {
            int e = idx / 7, i = idx - e * 7;
            xbuf[e * 8 + i] = xb[idx];
        }
        __syncthreads();

        // P1: layer 1, wave wv owns rows [16wv, 16wv+16); row 0 uses ego weights
        {
            const int e0 = wv * 16;
#pragma unroll 2
            for (int er = 0; er < 16; ++er) {
                const int e = e0 + er;
                float acc;
                if (e == 0) {
                    acc = b0e;
#pragma unroll
                    for (int i = 0; i < 7; ++i) acc = fmaf(xbuf[i], w0e[i], acc);
                } else {
                    acc = b0o;
#pragma unroll
                    for (int i = 0; i < 7; ++i) acc = fmaf(xbuf[e * 8 + i], w0o[i], acc);
                }
                Hb[e * STR + f] = fmaxf(acc, 0.f);
            }
        }
        __syncthreads();

        // P2: layer 2 (others rows, w1c registers) + ego layer-2 partials
        {
            const int e0 = wv * 16;
#pragma unroll 2
            for (int er = 0; er < 16; ++er) {
                const int e = e0 + er;
                if (e != 0) {
                    float acc = b1o;
                    const float4* hp = (const float4*)&Hb[e * STR];
#pragma unroll
                    for (int q4 = 0; q4 < 16; ++q4) {
                        float4 h = hp[q4];
                        acc = fmaf(h.x, w1c[4 * q4 + 0], acc);
                        acc = fmaf(h.y, w1c[4 * q4 + 1], acc);
                        acc = fmaf(h.z, w1c[4 * q4 + 2], acc);
                        acc = fmaf(h.w, w1c[4 * q4 + 3], acc);
                    }
                    Yb[e * STR + f] = fmaxf(acc, 0.f);
                }
            }
            // ego layer-2 partial over j in [16wv, 16wv+16) (ego_w1 streamed, L2-hot)
            float ep = 0.f;
#pragma unroll
            for (int jj = 0; jj < 16; ++jj) {
                const int j = wv * 16 + jj;
                ep = fmaf(Hb[j], ego_w1[j * 64 + f], ep);   // Hb row 0
            }
            egopart[wv * STR + f] = ep;
        }
        __syncthreads();

        // P3a: combine ego; keep fp32 copy in register for the residual
        const float ego_f = fmaxf(
            b1e + egopart[0 * STR + f] + egopart[1 * STR + f] +
                  egopart[2 * STR + f] + egopart[3 * STR + f], 0.f);
        if (wv == 0) Yb[0 * STR + f] = ego_f;
        __syncthreads();

        // P3b: q partials: q[f] = sum_j ego[j] * Wq[j][f]
        {
            float qp = 0.f;
#pragma unroll
            for (int jj = 0; jj < 16; ++jj) {
                const int j = wv * 16 + jj;
                qp = fmaf(Yb[j], Wq[j * 64 + f], qp);       // Yb row 0 = ego
            }
            qpart[wv * STR + f] = qp;
        }
        __syncthreads();

        // P4a: combine q
        {
            float qf = qpart[0 * STR + f] + qpart[1 * STR + f] +
                       qpart[2 * STR + f] + qpart[3 * STR + f];
            if (wv == 0) qbuf[f] = qf;
        }
        __syncthreads();

        // P4b: kq_h[f] = sum_d Wk[f][16h+d] * q[16h+d]   (wave wv = head)
        {
            float kqv = 0.f;
#pragma unroll
            for (int d = 0; d < 16; ++d) {
                kqv = fmaf(Wk[f * 64 + wv * 16 + d], qbuf[wv * 16 + d], kqv);
            }
            kqb[wv * STR + f] = kqv;
        }
        __syncthreads();

        // P4c: scores + softmax. wave wv = head; lane index = entity e
        {
            const int e = f;
            const float4* yp = (const float4*)&Yb[e * STR];
            const float4* kp = (const float4*)&kqb[wv * STR];
            float s = 0.f;
#pragma unroll
            for (int q4 = 0; q4 < 16; ++q4) {
                float4 yv = yp[q4], kv = kp[q4];
                s = fmaf(yv.x, kv.x, s); s = fmaf(yv.y, kv.y, s);
                s = fmaf(yv.z, kv.z, s); s = fmaf(yv.w, kv.w, s);
            }
            s *= 0.25f;                                // 1/sqrt(HD=16)
            if (xbuf[e * 8] < 0.5f) s = -1e9f;         // mask absent entities
            float m = s;
#pragma unroll
            for (int o = 32; o; o >>= 1) m = fmaxf(m, __shfl_xor(m, o));
            const float p = __expf(s - m);
            float sm = p;
#pragma unroll
            for (int o = 32; o; o >>= 1) sm += __shfl_xor(sm, o);
            pbuf[wv * STR + e] = p / sm;
        }
        __syncthreads();

        // P5: pY[h][f] = sum_e p[h][e] * Y[e][f]   (wave wv = head)
        {
            float acc = 0.f;
            const float4* pp = (const float4*)&pbuf[wv * STR];
#pragma unroll
            for (int e4 = 0; e4 < 16; ++e4) {
                float4 pv = pp[e4];
                acc = fmaf(pv.x, Yb[(4 * e4 + 0) * STR + f], acc);
                acc = fmaf(pv.y, Yb[(4 * e4 + 1) * STR + f], acc);
                acc = fmaf(pv.z, Yb[(4 * e4 + 2) * STR + f], acc);
                acc = fmaf(pv.w, Yb[(4 * e4 + 3) * STR + f], acc);
            }
            pYb[wv * STR + f] = acc;
        }
        __syncthreads();

        // P6: out64 partials: out64[f] = sum_i pY[f>>4][i] * Wv[i][f]
        {
            float op = 0.f;
#pragma unroll
            for (int ii = 0; ii < 16; ++ii) {
                const int i = wv * 16 + ii;
                op = fmaf(pYb[hf * STR + i], Wv[i * 64 + f], op);
            }
            opart[wv * STR + f] = op;
        }
        __syncthreads();

        // P7a: combine out64
        {
            float o64 = opart[0 * STR + f] + opart[1 * STR + f] +
                        opart[2 * STR + f] + opart[3 * STR + f];
            if (wv == 0) obuf[f] = o64;
        }
        __syncthreads();

        // P7b: result partials: sum_j out64[j] * Wc[j][f]
        {
            float rp = 0.f;
#pragma unroll
            for (int jj = 0; jj < 16; ++jj) {
                const int j = wv * 16 + jj;
                rp = fmaf(obuf[j], Wc[j * 64 + f], rp);
            }
            rpart[wv * STR + f] = rp;
        }
        __syncthreads();

        // P8: combine, residual, scale, store
        {
            float res = rpart[0 * STR + f] + rpart[1 * STR + f] +
                        rpart[2 * STR + f] + rpart[3 * STR + f];
            if (wv == 0) out[(size_t)b * 64 + f] = (res + ego_f) * 0.5f;
        }
        __syncthreads();   // protect LDS reuse across the batch loop
    }
}

extern "C" void kernel_launch(void* const* d_in, const int* in_sizes, int n_in,
                              void* d_out, int out_size, void* d_ws, size_t ws_size,
                              hipStream_t stream) {
    const float* x      = (const float*)d_in[0];
    const float* ego_w0 = (const float*)d_in[1];
    const float* ego_b0 = (const float*)d_in[2];
    const float* ego_w1 = (const float*)d_in[3];
    const float* ego_b1 = (const float*)d_in[4];
    const float* oth_w0 = (const float*)d_in[5];
    const float* oth_b0 = (const float*)d_in[6];
    const float* oth_w1 = (const float*)d_in[7];
    const float* oth_b1 = (const float*)d_in[8];
    const float* Wk     = (const float*)d_in[9];
    const float* Wv     = (const float*)d_in[10];
    const float* Wq     = (const float*)d_in[11];
    const float* Wc     = (const float*)d_in[12];

    const int BPB = 16;                 // 8192 batches / 512 blocks
    ego_attn_kernel<<<512, 256, 0, stream>>>(
        x, ego_w0, ego_b0, ego_w1, ego_b1,
        oth_w0, oth_b0, oth_w1, oth_b1,
        Wk, Wv, Wq, Wc,
        (float*)d_out, BPB);
}

// Round 3
// 211.926 us; speedup vs baseline: 1.1372x; 1.1372x over previous
//
#include <hip/hip_runtime.h>
#include <hip/hip_bf16.h>

// EgoAttentionNetwork: B=8192, E=64, F_IN=7, D=64, H=4, HD=16.  fp32 in/out.
// Round 3: MFMA layer-2 + barrier diet (12 -> 2 per batch) + 4 blocks/CU.
//   - wave wv owns entity rows [16wv, 16wv+16) end-to-end (x stage, layer1,
//     MFMA band) => those phases are wave-local, no __syncthreads.
//   - oth_w1 held as persistent MFMA B-frags (32 VGPRs); H staged bf16 in LDS
//     A-layout. Y accumulates fp32 (only H/W1 are bf16-rounded).
//   - q/kq computed redundantly per wave (shfl for transpose), head = wv.
//   - "leader" wave (rotates = bi&3) does the serial 1-row chains: ego MLP,
//     out = pY@Wv, result = out@Wc + residual.
// Barriers per batch: B3 (Yb complete, pre-scores), B4 (pYb complete, pre-tail).

typedef __attribute__((ext_vector_type(8))) short short8;  // 8 bf16
typedef __attribute__((ext_vector_type(4))) float f32x4;

#define STR 68   // fp32 LDS row stride (dwords)
#define HS  72   // bf16 LDS row stride (shorts) for A-layout H

__device__ __forceinline__ short f2bs(float x) {
    __hip_bfloat16 h = __float2bfloat16(x);
    return __builtin_bit_cast(short, h);
}

__global__ __launch_bounds__(256, 4)
void ego_attn_kernel(const float* __restrict__ x,
                     const float* __restrict__ ego_w0, const float* __restrict__ ego_b0,
                     const float* __restrict__ ego_w1, const float* __restrict__ ego_b1,
                     const float* __restrict__ oth_w0, const float* __restrict__ oth_b0,
                     const float* __restrict__ oth_w1, const float* __restrict__ oth_b1,
                     const float* __restrict__ Wk, const float* __restrict__ Wv,
                     const float* __restrict__ Wq, const float* __restrict__ Wc,
                     float* __restrict__ out, int batches_per_block)
{
    __shared__ __align__(16) float xbuf[64 * 8];    // x rows, stride 8
    __shared__ __align__(16) short Ha[64 * HS];     // H bf16, A-layout rows
    __shared__ __align__(16) float Yb[64 * STR];    // input_all fp32 (row0 = ego)
    __shared__ __align__(16) float hegob[64];       // ego layer-1 output
    __shared__ __align__(16) float kqb[4 * STR];    // per-head Wk.q
    __shared__ __align__(16) float pbuf[4 * STR];   // per-head softmax probs
    __shared__ __align__(16) float pYb[4 * STR];    // per-head p.Y
    __shared__ __align__(16) float obuf[64];        // attention output (leader)
    __shared__ float b1l[64];                       // oth_b1 (for MFMA cols)

    const int tid = threadIdx.x;
    const int wv  = tid >> 6;     // wave = row band = head
    const int f   = tid & 63;     // lane = feature column
    const int lg  = f >> 4;       // lane quad
    const int ln  = f & 15;

    // ---- persistent per-lane weights ----
    float w0o[7], w0e[7];
#pragma unroll
    for (int i = 0; i < 7; ++i) {
        w0o[i] = oth_w0[i * 64 + f];
        w0e[i] = ego_w0[i * 64 + f];
    }
    const float b0o = oth_b0[f], b0e = ego_b0[f], b1e = ego_b1[f];
    if (tid < 64) b1l[tid] = oth_b1[tid];
    if (wv == 0) Ha[f] = 0;       // row 0 never written again (ego path separate)

    // oth_w1 as MFMA B-frags: lane holds B[k=(lg*8+j)+32kc][n=16ct+ln]
    short8 bfr[2][4];
#pragma unroll
    for (int kc = 0; kc < 2; ++kc)
#pragma unroll
        for (int ct = 0; ct < 4; ++ct) {
            short8 v;
#pragma unroll
            for (int j = 0; j < 8; ++j) {
                const int k = kc * 32 + lg * 8 + j;
                v[j] = f2bs(oth_w1[k * 64 + ct * 16 + ln]);
            }
            bfr[kc][ct] = v;
        }
    __syncthreads();   // b1l / Ha row-0 visible

    for (int bi = 0; bi < batches_per_block; ++bi) {
        const int b = blockIdx.x * batches_per_block + bi;
        const float* xb = x + (size_t)b * 448;
        const bool isL = (wv == (bi & 3));   // rotating leader wave

        // stage own 16 x-rows (wave-local, coalesced)
        {
            const float* src = xb + wv * 112;
            for (int idx = f; idx < 112; idx += 64) {
                const int e = idx / 7, i = idx - e * 7;
                xbuf[(wv * 16 + e) * 8 + i] = src[idx];
            }
        }
        // leader: ego layer-1 (row 0, broadcast global reads)
        if (isL) {
            float a = b0e;
#pragma unroll
            for (int i = 0; i < 7; ++i) a = fmaf(xb[i], w0e[i], a);
            hegob[f] = fmaxf(a, 0.f);
        }
        // P1: layer-1 for own band -> Ha (bf16, A-layout rows)
#pragma unroll 4
        for (int er = 0; er < 16; ++er) {
            const int e = wv * 16 + er;
            if (e == 0) continue;            // wave-uniform skip
            float a = b0o;
#pragma unroll
            for (int i = 0; i < 7; ++i) a = fmaf(xbuf[e * 8 + i], w0o[i], a);
            Ha[e * HS + f] = f2bs(fmaxf(a, 0.f));
        }
        // leader: ego layer-2 (keep residual in reg, publish Yb row 0)
        float ego_f = 0.f;
        if (isL) {
            float a = b1e;
#pragma unroll 8
            for (int j = 0; j < 64; ++j) a = fmaf(hegob[j], ego_w1[j * 64 + f], a);
            ego_f = fmaxf(a, 0.f);
            Yb[f] = ego_f;
        }
        // P2: MFMA band: Y[16wv..+16][:] = relu(H @ oth_w1 + b1)
        {
            const int eb = wv * 16;
            const short8 a0 = *(const short8*)&Ha[(eb + ln) * HS + lg * 8];
            const short8 a1 = *(const short8*)&Ha[(eb + ln) * HS + lg * 8 + 32];
#pragma unroll
            for (int ct = 0; ct < 4; ++ct) {
                const float bv = b1l[ct * 16 + ln];
                f32x4 c = {bv, bv, bv, bv};
                c = __builtin_amdgcn_mfma_f32_16x16x32_bf16(a0, bfr[0][ct], c, 0, 0, 0);
                c = __builtin_amdgcn_mfma_f32_16x16x32_bf16(a1, bfr[1][ct], c, 0, 0, 0);
#pragma unroll
                for (int r = 0; r < 4; ++r) {
                    const int e = eb + lg * 4 + r;     // C-layout row
                    if (e != 0) Yb[e * STR + ct * 16 + ln] = fmaxf(c[r], 0.f);
                }
            }
        }
        __syncthreads();   // B3: all Yb rows (incl. ego row 0) visible

        // q[f] = ego . Wq[:,f]   (redundant per wave; Yb row 0 broadcast reads)
        float qf = 0.f;
#pragma unroll 4
        for (int j4 = 0; j4 < 16; ++j4) {
            const float4 y = *(const float4*)&Yb[4 * j4];
            qf = fmaf(y.x, Wq[(4 * j4 + 0) * 64 + f], qf);
            qf = fmaf(y.y, Wq[(4 * j4 + 1) * 64 + f], qf);
            qf = fmaf(y.z, Wq[(4 * j4 + 2) * 64 + f], qf);
            qf = fmaf(y.w, Wq[(4 * j4 + 3) * 64 + f], qf);
        }
        // kq_h[f] = sum_d Wk[f][16h+d] q[16h+d]  (h = wv; q via shfl)
        {
            float a = 0.f;
#pragma unroll
            for (int d = 0; d < 16; ++d) {
                const float qd = __shfl(qf, wv * 16 + d);
                a = fmaf(Wk[f * 64 + wv * 16 + d], qd, a);
            }
            kqb[wv * STR + f] = a;   // wave-own row; read back below (lgkm only)
        }
        // scores + softmax: lane = entity e, head = wv
        {
            const int e = f;
            float s = 0.f;
#pragma unroll 4
            for (int q4 = 0; q4 < 16; ++q4) {
                const float4 yv = *(const float4*)&Yb[e * STR + 4 * q4];
                const float4 kv = *(const float4*)&kqb[wv * STR + 4 * q4];
                s = fmaf(yv.x, kv.x, s); s = fmaf(yv.y, kv.y, s);
                s = fmaf(yv.z, kv.z, s); s = fmaf(yv.w, kv.w, s);
            }
            s *= 0.25f;                              // 1/sqrt(16)
            if (xbuf[e * 8] < 0.5f) s = -1e9f;       // absent-entity mask
            float m = s;
#pragma unroll
            for (int o = 32; o; o >>= 1) m = fmaxf(m, __shfl_xor(m, o));
            const float p = __expf(s - m);
            float sm = p;
#pragma unroll
            for (int o = 32; o; o >>= 1) sm += __shfl_xor(sm, o);
            pbuf[wv * STR + e] = p / sm;
        }
        // pY[h][f] = sum_e p[h][e] Y[e][f]
        {
            float a = 0.f;
#pragma unroll 4
            for (int e4 = 0; e4 < 16; ++e4) {
                const float4 pv = *(const float4*)&pbuf[wv * STR + 4 * e4];
                a = fmaf(pv.x, Yb[(4 * e4 + 0) * STR + f], a);
                a = fmaf(pv.y, Yb[(4 * e4 + 1) * STR + f], a);
                a = fmaf(pv.z, Yb[(4 * e4 + 2) * STR + f], a);
                a = fmaf(pv.w, Yb[(4 * e4 + 3) * STR + f], a);
            }
            pYb[wv * STR + f] = a;
        }
        __syncthreads();   // B4: pYb complete

        // leader tail: out64 = pY @ Wv (head-sliced), result = out @ Wc + res
        if (isL) {
            const int hf = f >> 4;
            float o = 0.f;
#pragma unroll 8
            for (int j = 0; j < 64; ++j)
                o = fmaf(pYb[hf * STR + j], Wv[j * 64 + f], o);
            obuf[f] = o;
            float r = 0.f;
#pragma unroll 8
            for (int j = 0; j < 64; ++j)
                r = fmaf(obuf[j], Wc[j * 64 + f], r);
            out[(size_t)b * 64 + f] = (r + ego_f) * 0.5f;
        }
        // no end barrier: next batch's cross-wave reads are fenced by its B3,
        // which the (slow) leader joins only after finishing this tail.
    }
}

extern "C" void kernel_launch(void* const* d_in, const int* in_sizes, int n_in,
                              void* d_out, int out_size, void* d_ws, size_t ws_size,
                              hipStream_t stream) {
    const float* x      = (const float*)d_in[0];
    const float* ego_w0 = (const float*)d_in[1];
    const float* ego_b0 = (const float*)d_in[2];
    const float* ego_w1 = (const float*)d_in[3];
    const float* ego_b1 = (const float*)d_in[4];
    const float* oth_w0 = (const float*)d_in[5];
    const float* oth_b0 = (const float*)d_in[6];
    const float* oth_w1 = (const float*)d_in[7];
    const float* oth_b1 = (const float*)d_in[8];
    const float* Wk     = (const float*)d_in[9];
    const float* Wv     = (const float*)d_in[10];
    const float* Wq     = (const float*)d_in[11];
    const float* Wc     = (const float*)d_in[12];

    const int BPB = 8;                  // 8192 batches / 1024 blocks -> 4 blocks/CU
    ego_attn_kernel<<<1024, 256, 0, stream>>>(
        x, ego_w0, ego_b0, ego_w1, ego_b1,
        oth_w0, oth_b0, oth_w1, oth_b1,
        Wk, Wv, Wq, Wc,
        (float*)d_out, BPB);
}